// Round 10
// baseline (355.407 us; speedup 1.0000x reference)
//
#include <hip/hip_runtime.h>

// MemN2N: B=64, S=4096, D=256, hops=3 (fp32).
// Algebraic reduction: softmax over a size-1 axis == 1 -> attention weights
// are the memory-validity mask, hop-independent:
//   x_b = sum_{s < len_b - 1} sentences[b,s,:]
//   out_b = q0_b + hops sequential adds of (x_b @ W)
// Evidence so far: totals 350-355 us across 3-kernel/2-kernel, CHUNKS 32/64,
// three different block->work maps => colsum scheduling is NOT the binding
// term. Harness floor ~252 us (1 GiB ws poison 162 + d_in restore ~78,
// measured round 3). This round: remove the one structure common to all
// neutral variants — the per-block mask popcount prologue (4096 blocks x 16
// strided loads + a mask[0] hot-word stampede) — via a tiny k_lengths kernel.
//   k_lengths: 64 blocks, popcount one mask row each -> lengths[64]
//   k_colsum : 4096 blocks (b fast, heavy-first, 2x oversubscribed), prologue
//              = one scalar L2 load of lengths[b]
//   k_final  : 64 blocks, combine + GEMV + epilogue, same scalar prologue

#define BN 64
#define SN 4096
#define DN 256
#define CHUNKS 64
#define CHUNK_ROWS (SN / CHUNKS) // 64

// ---------------- Kernel A: per-example valid lengths ----------------
// Mask dtype detected from word 0 (len >= 2 => first two elements true):
//   1 -> int32 0/1; 0x3f800000 -> f32 1.0 (defensive); else bool bytes.
__global__ __launch_bounds__(256)
void k_lengths(const unsigned int* __restrict__ mask_words,
               int* __restrict__ lengths) {
    const int b = blockIdx.x;
    const int t = threadIdx.x;
    const unsigned int w0 = mask_words[0];
    const int mode = (w0 == 1u) ? 0 : (w0 == 0x3f800000u) ? 1 : 2;
    const int wpr = (mode == 2) ? (SN / 4) : SN;
    const unsigned int* row = mask_words + (size_t)b * wpr;
    int sum = 0;
    for (int i = t; i < wpr; i += 256) {
        const unsigned int w = row[i];
        sum += (mode == 2) ? __popc(w) : (mode == 0 ? (int)w : (w != 0u ? 1 : 0));
    }
    #pragma unroll
    for (int off = 32; off > 0; off >>= 1)
        sum += __shfl_down(sum, off, 64);
    __shared__ int red[4];
    if ((t & 63) == 0) red[t >> 6] = sum;
    __syncthreads();
    if (t == 0)
        lengths[b] = red[0] + red[1] + red[2] + red[3];
}

// ---------------- Kernel B: chunked masked column-sum ----------------
__global__ __launch_bounds__(256)
void k_colsum(const float* __restrict__ sent,
              const int* __restrict__ lengths,
              float* __restrict__ partials) {      // [BN][CHUNKS][DN]
    const int id = blockIdx.x;                     // b fast, c slow:
    const int b = id & (BN - 1);                   // heavy (low-c) blocks
    const int c = id >> 6;                         // dispatch first
    const int t = threadIdx.x;

    const int limit = lengths[b] - 1;              // memory rows: s < limit

    const int s0 = c * CHUNK_ROWS;
    const int d4 = (t & 63) * 4;                   // 4 contiguous columns
    const int g = t >> 6;                          // row group 0..3
    float4 acc = make_float4(0.f, 0.f, 0.f, 0.f);
    int nrows = limit - s0;
    if (nrows > CHUNK_ROWS) nrows = CHUNK_ROWS;
    if (nrows > 0) {
        const float* base = sent + ((size_t)b * SN + s0) * DN + d4;
        #pragma unroll 4
        for (int r = g; r < nrows; r += 4) {
            const float4 v = *reinterpret_cast<const float4*>(base + (size_t)r * DN);
            acc.x += v.x; acc.y += v.y; acc.z += v.z; acc.w += v.w;
        }
    }
    __shared__ float4 red[256];
    red[t] = acc;
    __syncthreads();
    if (t < 64) {
        const float4 a0 = red[t], a1 = red[64 + t], a2 = red[128 + t], a3 = red[192 + t];
        float4 o;
        o.x = a0.x + a1.x + a2.x + a3.x;
        o.y = a0.y + a1.y + a2.y + a3.y;
        o.z = a0.z + a1.z + a2.z + a3.z;
        o.w = a0.w + a1.w + a2.w + a3.w;
        reinterpret_cast<float4*>(partials + ((size_t)b * CHUNKS + c) * DN)[t] = o;
    }
}

// ---------------- Kernel C: combine + GEMV + epilogue ----------------
__global__ __launch_bounds__(256)
void k_final(const float* __restrict__ sent,
             const int* __restrict__ lengths,
             const float* __restrict__ Wm,
             const int* __restrict__ hops_ptr,
             const float* __restrict__ partials,
             float* __restrict__ out) {
    const int b = blockIdx.x;
    const int t = threadIdx.x;                     // == d, 256 threads
    const int limit = lengths[b] - 1;

    float x = 0.f;
    const float* p = partials + (size_t)b * CHUNKS * DN + t;
    #pragma unroll 8
    for (int k = 0; k < CHUNKS; ++k)
        x += p[k * DN];
    __shared__ float xs[DN];
    xs[t] = x;
    __syncthreads();
    const float q0 = sent[((size_t)b * SN + limit) * DN + t];
    float gv = 0.f;
    #pragma unroll 8
    for (int k = 0; k < DN; ++k)
        gv = fmaf(xs[k], Wm[k * DN + t], gv);
    const int hops = hops_ptr[0];
    float r = q0;
    for (int i = 0; i < hops; ++i)                 // match reference add order
        r += gv;
    out[b * DN + t] = r;
}

extern "C" void kernel_launch(void* const* d_in, const int* in_sizes, int n_in,
                              void* d_out, int out_size, void* d_ws, size_t ws_size,
                              hipStream_t stream) {
    const float* sent = (const float*)d_in[0];
    const unsigned int* mask = (const unsigned int*)d_in[1];
    const float* Wm = (const float*)d_in[2];
    const int* hops = (const int*)d_in[3];
    float* out = (float*)d_out;

    // ws layout: [0,256) lengths (64 ints); [1024, 1024+4MB) partials
    int* lengths = (int*)d_ws;
    float* partials = (float*)((char*)d_ws + 1024);

    k_lengths<<<dim3(BN), dim3(256), 0, stream>>>(mask, lengths);
    k_colsum<<<dim3(CHUNKS * BN), dim3(256), 0, stream>>>(sent, lengths, partials);
    k_final<<<dim3(BN), dim3(256), 0, stream>>>(sent, lengths, Wm, hops, partials, out);
}